// Round 4
// baseline (897.450 us; speedup 1.0000x reference)
//
#include <hip/hip_runtime.h>
#include <stdint.h>

#define N_NODES 50000
#define N_PAD   50048                // padded to 128-row multiple for gemm tiles
#define NNZ     800000
#define SUP     3
#define D_IN    512
#define D_OUT   256
#define TOT_E   (SUP * NNZ)          // 2,400,000
#define NBUCK   391                  // ceil(50000/128) : 128-row buckets
#define CAP     6976                 // per-bucket capacity (mean 6138, +10 sigma)
#define CHUNK   3072                 // edges per bucket block (782 blocks, 4/CU)
#define NBB     782                  // ceil(TOT_E / CHUNK)
#define NCB     37                   // col blocks: ceil(150000 / 4096) -> 2MB pre window
#define NBIN    (128 * NCB)          // 4736 sort bins (row-major, colblock minor)
#define NB_WPREP 1536                // 393216 / 256
#define NB_XPREP 12500               // 3,200,000 / 256
#define NB_GEMM  2346                // 391 m-tiles * 6 (n-tile x support)
#define SPMM_NB  1536                // 6 blocks/CU x 256 CU: all co-resident
#define NWAVES   (SPMM_NB * 4)       // 6144 waves
#define ROWS_PW  9                   // max rows per wave (ranges computed exactly)

typedef __attribute__((ext_vector_type(8))) short bf16x8;
typedef __attribute__((ext_vector_type(4))) float f32x4;
typedef __attribute__((address_space(3))) unsigned int lds_u32_t;
typedef const __attribute__((address_space(1))) unsigned int glb_u32_t;

static __device__ __forceinline__ unsigned short f2bf(float f) {
    unsigned int u = __float_as_uint(f);
    unsigned int r = (u + 0x7fffu + ((u >> 16) & 1u)) >> 16;
    return (unsigned short)r;
}
static __device__ __forceinline__ unsigned int pack_bf2(float lo, float hi) {
    unsigned int a = __float_as_uint(lo) + 0x8000u;
    unsigned int b = __float_as_uint(hi) + 0x8000u;
    return (a >> 16) | (b & 0xffff0000u);
}
static __device__ __forceinline__ float bf2f(unsigned short h) {
    return __uint_as_float(((unsigned int)h) << 16);
}
static __device__ __forceinline__ int2 ldnt_int2(const int2* p) {
    long long v = __builtin_nontemporal_load((const long long*)p);
    int2 r;
    r.x = (int)(v & 0xffffffffLL);
    r.y = (int)(v >> 32);
    return r;
}

// ============ prep: pure streaming conversions, zero LDS (8 blk/CU) ==============
__global__ __launch_bounds__(256) void prep_kernel(const float* __restrict__ x,
                                                   unsigned int* __restrict__ xb,
                                                   const float* __restrict__ W,
                                                   unsigned short* __restrict__ Wt) {
    const int blk = blockIdx.x;
    const int tid = threadIdx.x;
    if (blk < NB_XPREP) {
        int idx = blk * 256 + tid;                 // < 3,200,000 exactly
        const f32x4* src = (const f32x4*)(x) + idx * 2;
        f32x4 f0 = __builtin_nontemporal_load(src);
        f32x4 f1 = __builtin_nontemporal_load(src + 1);
        uint4 o;
        o.x = pack_bf2(f0.x, f0.y);
        o.y = pack_bf2(f0.z, f0.w);
        o.z = pack_bf2(f1.x, f1.y);
        o.w = pack_bf2(f1.z, f1.w);
        *((uint4*)xb + idx) = o;
    } else {
        int idx = (blk - NB_XPREP) * 256 + tid;    // < 393216 exactly
        int n = idx & (D_OUT - 1);
        int k = (idx >> 8) & (D_IN - 1);
        int s = idx >> 17;
        Wt[((size_t)s * D_OUT + n) * D_IN + k] = f2bf(W[idx]);
    }
}

// ============ bucket: edges by row>>7, coalesced run writes (782 blocks) =========
__global__ __launch_bounds__(256) void bucket_kernel(const int* __restrict__ rows,
                                                     const int* __restrict__ cols,
                                                     const float* __restrict__ vals,
                                                     const float* __restrict__ cw,
                                                     int* __restrict__ bucket_cursor,
                                                     int2* __restrict__ buck) {
    __shared__ double smem8[4750];           // 38000 B -> 4 blocks/CU
    char* smem = (char*)smem8;
    const int blk = blockIdx.x;
    const int tid = threadIdx.x;

    int2* stage = (int2*)smem;                               // 24576 B
    unsigned short* bucket_of = (unsigned short*)(smem + 24576); // 6144 B
    int* hist   = (int*)(smem + 30720);                      // [391]
    int* sc     = hist + NBUCK;                              // [256]
    int* sstart = sc + 256;                                  // [391]
    int* lcur   = sstart + NBUCK;                            // [391]
    int* gbase  = lcur + NBUCK;                              // [391]

    const int base_n = blk * CHUNK;
    const int count = min(CHUNK, TOT_E - base_n);
    float cw0 = cw[0], cw1 = cw[1], cw2 = cw[2];

    for (int i = tid; i < NBUCK; i += 256) hist[i] = 0;
    __syncthreads();
    for (int i = tid; i < count; i += 256)
        atomicAdd(&hist[rows[base_n + i] >> 7], 1);
    __syncthreads();
    int b0 = 2 * tid, b1 = b0 + 1;
    int h0 = (b0 < NBUCK) ? hist[b0] : 0;
    int h1 = (b1 < NBUCK) ? hist[b1] : 0;
    sc[tid] = h0 + h1;
    __syncthreads();
    for (int off = 1; off < 256; off <<= 1) {
        int t = (tid >= off) ? sc[tid - off] : 0;
        __syncthreads();
        sc[tid] += t;
        __syncthreads();
    }
    int excl = sc[tid] - (h0 + h1);
    if (b0 < NBUCK) { sstart[b0] = excl;      lcur[b0] = excl; }
    if (b1 < NBUCK) { sstart[b1] = excl + h0; lcur[b1] = excl + h0; }
    for (int i = tid; i < NBUCK; i += 256)
        gbase[i] = atomicAdd(&bucket_cursor[i], hist[i]);
    __syncthreads();
    for (int i = tid; i < count; i += 256) {
        int n = base_n + i;
        int r = rows[n];
        int c = __builtin_nontemporal_load(&cols[n]);
        float v = __builtin_nontemporal_load(&vals[n]);
        int s = n / NNZ;
        float w = v * (s == 0 ? cw0 : (s == 1 ? cw1 : cw2));
        int b = r >> 7;
        int p = atomicAdd(&lcur[b], 1);
        stage[p] = make_int2(((r & 127) << 18) | (s * N_NODES + c), __float_as_int(w));
        bucket_of[p] = (unsigned short)b;
    }
    __syncthreads();
    for (int i = tid; i < count; i += 256) {
        int b = bucket_of[i];
        int local_off = i - sstart[b];
        buck[(size_t)b * CAP + gbase[b] + local_off] = stage[i];
    }
}

// ============ sort: counting sort by (row_local, colblock) -> cache-friendly CSR ==
__global__ __launch_bounds__(256) void sort_kernel(const int2* __restrict__ buck,
                                                   const int* __restrict__ bucket_cursor,
                                                   int2* __restrict__ cv,
                                                   int* __restrict__ base,
                                                   int* __restrict__ cnt) {
    __shared__ double smem8[9537];           // 76296 B -> 2 blocks/CU
    char* smem = (char*)smem8;
    const int tid = threadIdx.x;

    int2* stage   = (int2*)smem;                     // 55808 B
    int* hist     = (int*)(smem + 55808);            // [4736] -> starts -> cursors
    int* sc       = hist + NBIN;                     // [256]
    int* rowstart = sc + 256;                        // [129]

    const int b = blockIdx.x;
    const int sz = bucket_cursor[b];
    const int2* src = buck + (size_t)b * CAP;

    for (int i = tid; i < NBIN; i += 256) hist[i] = 0;
    __syncthreads();
    for (int i = tid; i < sz; i += 256) {
        int key = src[i].x;
        int bin = (key >> 18) * NCB + ((key & 0x3FFFF) >> 12);
        atomicAdd(&hist[bin], 1);
    }
    __syncthreads();
    // chunked exclusive scan over 4736 bins (19 bins/thread)
    const int lo = tid * 19;
    const int hi = min(lo + 19, NBIN);
    int acc = 0;
    for (int i = lo; i < hi; ++i) acc += hist[i];
    sc[tid] = acc;
    __syncthreads();
    for (int off = 1; off < 256; off <<= 1) {
        int t = (tid >= off) ? sc[tid - off] : 0;
        __syncthreads();
        sc[tid] += t;
        __syncthreads();
    }
    int run = sc[tid] - acc;                 // exclusive offset of this chunk
    for (int i = lo; i < hi; ++i) {
        int h = hist[i];
        hist[i] = run;
        run += h;
    }
    __syncthreads();
    if (tid < 128) rowstart[tid] = hist[tid * NCB];
    if (tid == 0)  rowstart[128] = sz;
    __syncthreads();
    for (int i = tid; i < sz; i += 256) {
        int2 e = src[i];
        int key = e.x;
        int bin = (key >> 18) * NCB + ((key & 0x3FFFF) >> 12);
        int p = atomicAdd(&hist[bin], 1);
        stage[p] = make_int2(key & 0x3FFFF, e.y);
    }
    __syncthreads();
    size_t gb = (size_t)b * CAP;
    for (int i = tid; i < sz; i += 256) cv[gb + i] = stage[i];
    int r = b * 128 + tid;
    if (tid < 128 && r < N_NODES) {
        base[r] = (int)gb + rowstart[tid];
        cnt[r]  = rowstart[tid + 1] - rowstart[tid];
    }
}

// ============ m97-style bf16 MFMA GEMM: pre[s] = xb @ Wt[s]^T (32KB LDS) =========
__global__ __launch_bounds__(256) void gemm_kernel(const unsigned short* __restrict__ xb,
                                                   const unsigned short* __restrict__ Wt,
                                                   unsigned short* __restrict__ pre) {
    __shared__ unsigned short lds_a[128 * 64];    // 16384 B
    __shared__ unsigned short lds_b[128 * 64];    // 16384 B
    const int blk = blockIdx.x;
    const int tid = threadIdx.x;

    // XCD-chunked bijective swizzle: the 6 sharers of an m-tile land on one XCD
    constexpr int SWQ = NB_GEMM / 8;   // 293
    constexpr int SWR = NB_GEMM % 8;   // 2
    const int xcd = blk & 7, pos = blk >> 3;
    const int my = (xcd < SWR ? xcd * (SWQ + 1)
                              : SWR * (SWQ + 1) + (xcd - SWR) * SWQ) + pos;
    const int mt  = my / 6;
    const int rem = my % 6;                // sharers of m-tile adjacent
    const int m0 = mt * 128;
    const int n0 = (rem & 1) * 128;
    const int s  = rem >> 1;
    const unsigned short* wt = Wt + (size_t)s * D_OUT * D_IN;
    const int wave = tid >> 6;
    const int lane = tid & 63;
    const int quad = lane >> 4;
    const int lo   = lane & 15;
    const int wm = (wave & 1) * 64;
    const int wn = (wave >> 1) * 64;

    f32x4 acc[4][4] = {};

    for (int kb = 0; kb < D_IN; kb += 64) {
        __syncthreads();
        #pragma unroll
        for (int c = 0; c < 4; ++c) {
            int idx = c * 256 + tid;
            int row = idx >> 3;
            int kp  = idx & 7;
            const unsigned short* ga = xb + (size_t)(m0 + row) * D_IN + kb + kp * 8;
            __builtin_amdgcn_global_load_lds((glb_u32_t*)ga,
                                             (lds_u32_t*)&lds_a[idx * 8], 16, 0, 0);
            const unsigned short* gb = wt + (size_t)(n0 + row) * D_IN + kb + kp * 8;
            __builtin_amdgcn_global_load_lds((glb_u32_t*)gb,
                                             (lds_u32_t*)&lds_b[idx * 8], 16, 0, 0);
        }
        __syncthreads();

        #pragma unroll
        for (int t = 0; t < 2; ++t) {
            bf16x8 af[4], bfr[4];
            #pragma unroll
            for (int i = 0; i < 4; ++i)
                af[i] = *(const bf16x8*)&lds_a[(wm + 16 * i + lo) * 64 + t * 32 + quad * 8];
            #pragma unroll
            for (int j = 0; j < 4; ++j)
                bfr[j] = *(const bf16x8*)&lds_b[(wn + 16 * j + lo) * 64 + t * 32 + quad * 8];
            #pragma unroll
            for (int i = 0; i < 4; ++i)
                #pragma unroll
                for (int j = 0; j < 4; ++j)
                    acc[i][j] = __builtin_amdgcn_mfma_f32_16x16x32_bf16(af[i], bfr[j], acc[i][j], 0, 0, 0);
        }
    }

    // epilogue: C layout col=lane&15, row=quad*4+reg
    #pragma unroll
    for (int i = 0; i < 4; ++i) {
        #pragma unroll
        for (int j = 0; j < 4; ++j) {
            int gn = n0 + wn + 16 * j + lo;
            #pragma unroll
            for (int r = 0; r < 4; ++r) {
                int gm2 = m0 + wm + 16 * i + quad * 4 + r;
                if (gm2 < N_NODES)
                    pre[((size_t)s * N_NODES + gm2) * D_OUT + gn] = f2bf(acc[i][j][r]);
            }
        }
    }
}

// ---------------- SpMM + ReLU: co-resident colblock-synchronous sweep -------------
// 1536 blocks (6/CU, all resident). Each wave owns <=9 consecutive rows with one
// cursor per row. Outer loop over 37 colblocks: in step cb every wave processes
// only its edges with col>>12 == cb (lists are (row,colblock)-sorted), so all
// 6144 waves gather from the same ~2-10 MB window of pre simultaneously -> L2-hot.
__global__ __launch_bounds__(256, 6) void spmm_kernel(const unsigned short* __restrict__ pre,
                                                      const int* __restrict__ base,
                                                      const int* __restrict__ cnt,
                                                      const int2* __restrict__ cv,
                                                      float* __restrict__ out) {
    const int wid  = blockIdx.x * 4 + (threadIdx.x >> 6);
    const int lane = threadIdx.x & 63;
    const int rs = (int)(((long)wid * N_NODES) / NWAVES);
    const int re = (int)(((long)(wid + 1) * N_NODES) / NWAVES);

    int j[ROWS_PW], je[ROWS_PW];
    f32x4 acc[ROWS_PW];
    #pragma unroll
    for (int r = 0; r < ROWS_PW; ++r) {
        int row = rs + r;
        bool v = row < re;
        int b = v ? base[row] : 0;
        j[r]  = b;
        je[r] = v ? b + cnt[row] : b;
        acc[r].x = 0.f; acc[r].y = 0.f; acc[r].z = 0.f; acc[r].w = 0.f;
    }

    const unsigned short* prel = pre + lane * 4;

    for (int cb = 0; cb < NCB; ++cb) {
        #pragma unroll
        for (int r = 0; r < ROWS_PW; ++r) {
            int jj = j[r];
            const int end = je[r];
            while (jj < end) {
                int2 e = ldnt_int2(&cv[jj]);
                if ((e.x >> 12) != cb) break;
                float w = __int_as_float(e.y);
                ushort4 p = *(const ushort4*)(prel + (size_t)e.x * D_OUT);
                acc[r].x += w * bf2f(p.x);
                acc[r].y += w * bf2f(p.y);
                acc[r].z += w * bf2f(p.z);
                acc[r].w += w * bf2f(p.w);
                ++jj;
            }
            j[r] = jj;
        }
    }

    #pragma unroll
    for (int r = 0; r < ROWS_PW; ++r) {
        int row = rs + r;
        if (row < re) {
            f32x4 o;
            o.x = fmaxf(acc[r].x, 0.f);
            o.y = fmaxf(acc[r].y, 0.f);
            o.z = fmaxf(acc[r].z, 0.f);
            o.w = fmaxf(acc[r].w, 0.f);
            __builtin_nontemporal_store(o, (f32x4*)(out + (size_t)row * D_OUT + lane * 4));
        }
    }
}

extern "C" void kernel_launch(void* const* d_in, const int* in_sizes, int n_in,
                              void* d_out, int out_size, void* d_ws, size_t ws_size,
                              hipStream_t stream) {
    const float* x    = (const float*)d_in[0];
    const float* W    = (const float*)d_in[1];
    const int*   rows = (const int*)d_in[2];
    const int*   cols = (const int*)d_in[3];
    const float* vals = (const float*)d_in[4];
    const float* cw   = (const float*)d_in[5];
    float* out = (float*)d_out;

    char* ws = (char*)d_ws;
    size_t off = 0;
    auto alloc = [&](size_t bytes) -> void* {
        void* p = ws + off;
        off += (bytes + 255) & ~(size_t)255;
        return p;
    };
    unsigned short* pre  = (unsigned short*)alloc((size_t)SUP * N_NODES * D_OUT * 2); // 76.8 MB
    unsigned short* xb   = (unsigned short*)alloc((size_t)N_PAD * D_IN * 2);          // 51.25 MB
    unsigned short* Wt   = (unsigned short*)alloc((size_t)SUP * D_OUT * D_IN * 2);    // 0.8 MB
    int* base            = (int*)alloc((size_t)N_NODES * 4);
    int* cnt             = (int*)alloc((size_t)N_NODES * 4);
    int* bucket_cursor   = (int*)alloc((size_t)NBUCK * 4);
    int2* cv             = (int2*)alloc((size_t)NBUCK * CAP * 8);                     // 21.8 MB
    // buck lives in d_out (51.2 MB >= 21.8 MB): written by bucket, read by sort,
    // dead before spmm overwrites out.
    int2* buck           = (int2*)d_out;

    hipMemsetAsync(bucket_cursor, 0, (size_t)NBUCK * 4, stream);

    bucket_kernel<<<NBB, 256, 0, stream>>>(rows, cols, vals, cw, bucket_cursor, buck);
    prep_kernel<<<NB_XPREP + NB_WPREP, 256, 0, stream>>>(x, (unsigned int*)xb, W, Wt);
    sort_kernel<<<NBUCK, 256, 0, stream>>>(buck, bucket_cursor, cv, base, cnt);
    gemm_kernel<<<NB_GEMM, 256, 0, stream>>>(xb, Wt, pre);
    spmm_kernel<<<SPMM_NB, 256, 0, stream>>>(pre, base, cnt, cv, out);
}

// Round 5
// 477.740 us; speedup vs baseline: 1.8785x; 1.8785x over previous
//
#include <hip/hip_runtime.h>
#include <stdint.h>

#define N_NODES 50000
#define N_PAD   50048                // padded to 128-row multiple for gemm tiles
#define NNZ     800000
#define SUP     3
#define D_IN    512
#define D_OUT   256
#define TOT_E   (SUP * NNZ)          // 2,400,000
#define NBUCK   782                  // ceil(50000/64) : 64-row buckets
#define CAP     3680                 // per-bucket capacity (mean 3069, +11 sigma)
#define CHUNK   3072                 // edges per bucket block
#define NBB     782                  // ceil(TOT_E / CHUNK)
#define NB_WPREP 1536                // 393216 / 256
#define NB_XPREP 12500               // 3,200,000 / 256
#define NB_GEMM  2346                // 391 m-tiles * 6 (n-tile x support)

typedef __attribute__((ext_vector_type(8))) short bf16x8;
typedef __attribute__((ext_vector_type(4))) float f32x4;
typedef __attribute__((address_space(3))) unsigned int lds_u32_t;
typedef const __attribute__((address_space(1))) unsigned int glb_u32_t;

static __device__ __forceinline__ unsigned short f2bf(float f) {
    unsigned int u = __float_as_uint(f);
    unsigned int r = (u + 0x7fffu + ((u >> 16) & 1u)) >> 16;
    return (unsigned short)r;
}
static __device__ __forceinline__ unsigned int pack_bf2(float lo, float hi) {
    unsigned int a = __float_as_uint(lo) + 0x8000u;
    unsigned int b = __float_as_uint(hi) + 0x8000u;
    return (a >> 16) | (b & 0xffff0000u);
}
static __device__ __forceinline__ float bf2f(unsigned short h) {
    return __uint_as_float(((unsigned int)h) << 16);
}
static __device__ __forceinline__ int2 ldnt_int2(const int2* p) {
    long long v = __builtin_nontemporal_load((const long long*)p);
    int2 r;
    r.x = (int)(v & 0xffffffffLL);
    r.y = (int)(v >> 32);
    return r;
}

// ============ fused: [0,782) bucket | [782,13282) xprep | [13282,14818) wprep ====
// Bucket (44KB LDS) runs concurrently with the streaming conversions; the LDS
// union caps streaming blocks at 3/CU (acceptable: they overlap bucket's time).
__global__ __launch_bounds__(256) void prepbucket_kernel(const int* __restrict__ rows,
                                                         const int* __restrict__ cols,
                                                         const float* __restrict__ vals,
                                                         const float* __restrict__ cw,
                                                         int* __restrict__ bucket_cursor,
                                                         int2* __restrict__ buck,
                                                         const float* __restrict__ x,
                                                         unsigned int* __restrict__ xb,
                                                         const float* __restrict__ W,
                                                         unsigned short* __restrict__ Wt) {
    __shared__ double smem8[5536];           // 44288 B -> 3 blocks/CU
    char* smem = (char*)smem8;
    const int blk = blockIdx.x;
    const int tid = threadIdx.x;

    if (blk < NBB) {
        // ---- bucket: edges by row>>6, coalesced run writes ----
        int2* stage = (int2*)smem;                               // 24576 B
        unsigned short* bucket_of = (unsigned short*)(smem + 24576); // 6144 B
        int* hist   = (int*)(smem + 30720);                      // [782]
        int* sc     = (int*)(smem + 33848);                      // [256]
        int* sstart = (int*)(smem + 34872);                      // [782]
        int* lcur   = (int*)(smem + 38000);                      // [782]
        int* gbase  = (int*)(smem + 41128);                      // [782]

        const int base_n = blk * CHUNK;
        const int count = min(CHUNK, TOT_E - base_n);
        float cw0 = cw[0], cw1 = cw[1], cw2 = cw[2];

        for (int i = tid; i < NBUCK; i += 256) hist[i] = 0;
        __syncthreads();
        for (int i = tid; i < count; i += 256)
            atomicAdd(&hist[rows[base_n + i] >> 6], 1);
        __syncthreads();
        // chunked exclusive scan over 782 bins (4 bins/thread)
        const int lo = tid * 4;
        const int hi = min(lo + 4, NBUCK);
        int acc = 0;
        for (int i = lo; i < hi; ++i) acc += hist[i];
        sc[tid] = acc;
        __syncthreads();
        for (int off = 1; off < 256; off <<= 1) {
            int t = (tid >= off) ? sc[tid - off] : 0;
            __syncthreads();
            sc[tid] += t;
            __syncthreads();
        }
        int run = sc[tid] - acc;
        for (int i = lo; i < hi; ++i) {
            int h = hist[i];
            sstart[i] = run;
            lcur[i]   = run;
            run += h;
        }
        __syncthreads();
        for (int i = tid; i < NBUCK; i += 256)
            gbase[i] = atomicAdd(&bucket_cursor[i], hist[i]);
        __syncthreads();
        for (int i = tid; i < count; i += 256) {
            int n = base_n + i;
            int r = rows[n];
            int c = __builtin_nontemporal_load(&cols[n]);
            float v = __builtin_nontemporal_load(&vals[n]);
            int s = n / NNZ;
            float w = v * (s == 0 ? cw0 : (s == 1 ? cw1 : cw2));
            int b = r >> 6;
            int p = atomicAdd(&lcur[b], 1);
            stage[p] = make_int2(((r & 63) << 18) | (s * N_NODES + c), __float_as_int(w));
            bucket_of[p] = (unsigned short)b;
        }
        __syncthreads();
        for (int i = tid; i < count; i += 256) {
            int b = bucket_of[i];
            int local_off = i - sstart[b];
            buck[(size_t)b * CAP + gbase[b] + local_off] = stage[i];
        }
    } else if (blk < NBB + NB_XPREP) {
        // ---- xprep: x fp32 -> bf16, 8 elems/thread ----
        int idx = (blk - NBB) * 256 + tid;         // < 3,200,000 exactly
        const f32x4* src = (const f32x4*)(x) + idx * 2;
        f32x4 f0 = __builtin_nontemporal_load(src);
        f32x4 f1 = __builtin_nontemporal_load(src + 1);
        uint4 o;
        o.x = pack_bf2(f0.x, f0.y);
        o.y = pack_bf2(f0.z, f0.w);
        o.z = pack_bf2(f1.x, f1.y);
        o.w = pack_bf2(f1.z, f1.w);
        *((uint4*)xb + idx) = o;
    } else {
        // ---- wprep: W[s][k][n] -> Wt[s][n][k], bf16 ----
        int idx = (blk - NBB - NB_XPREP) * 256 + tid;   // < 393216 exactly
        int n = idx & (D_OUT - 1);
        int k = (idx >> 8) & (D_IN - 1);
        int s = idx >> 17;
        Wt[((size_t)s * D_OUT + n) * D_IN + k] = f2bf(W[idx]);
    }
}

// ============ fused: [0,782) sort | [782,3128) gemm ==============================
// Sort (30.5KB) fits inside gemm's 32KB LDS union -> gemm keeps ~5 blocks/CU
// (vs round-0's 57.9KB union that halved gemm occupancy). Sort hides under gemm.
__global__ __launch_bounds__(256) void sortgemm_kernel(const int2* __restrict__ buck,
                                                       const int* __restrict__ bucket_cursor,
                                                       int2* __restrict__ cv,
                                                       int* __restrict__ base,
                                                       int* __restrict__ cnt,
                                                       const unsigned short* __restrict__ xb,
                                                       const unsigned short* __restrict__ Wt,
                                                       unsigned short* __restrict__ pre) {
    __shared__ double smem8[4096];           // 32768 B union
    char* smem = (char*)smem8;
    const int blk = blockIdx.x;
    const int tid = threadIdx.x;

    if (blk < NBUCK) {
        // ---- sort one 64-row bucket via LDS, emit CSR + base/cnt ----
        int2* stage = (int2*)smem;                   // 29440 B
        int* hist   = (int*)(smem + 29440);          // [64]
        int* sc     = (int*)(smem + 29696);          // [64]
        int* sstart = (int*)(smem + 29952);          // [64]
        int* cur    = (int*)(smem + 30208);          // [64]

        const int b = blk;
        const int sz = bucket_cursor[b];
        const int2* src = buck + (size_t)b * CAP;

        if (tid < 64) hist[tid] = 0;
        __syncthreads();
        for (int i = tid; i < sz; i += 256)
            atomicAdd(&hist[((unsigned)src[i].x) >> 18], 1);
        __syncthreads();
        if (tid < 64) sc[tid] = hist[tid];
        __syncthreads();
        for (int off = 1; off < 64; off <<= 1) {
            int t = (tid >= off && tid < 64) ? sc[tid - off] : 0;
            __syncthreads();
            if (tid < 64) sc[tid] += t;
            __syncthreads();
        }
        if (tid < 64) {
            int st = sc[tid] - hist[tid];
            sstart[tid] = st;
            cur[tid] = st;
        }
        __syncthreads();
        for (int i = tid; i < sz; i += 256) {
            int2 e = src[i];
            int rl = ((unsigned)e.x) >> 18;
            int p = atomicAdd(&cur[rl], 1);
            stage[p] = make_int2(e.x & 0x3FFFF, e.y);
        }
        __syncthreads();
        size_t gb = (size_t)b * CAP;
        for (int i = tid; i < sz; i += 256) cv[gb + i] = stage[i];
        int r = b * 64 + tid;
        if (tid < 64 && r < N_NODES) {
            base[r] = (int)gb + sstart[tid];
            cnt[r]  = hist[tid];
        }
    } else {
        // ---- m97-style bf16 MFMA GEMM: pre[s] = xb @ Wt[s]^T ----
        unsigned short* lds_a = (unsigned short*)smem;            // 16384 B
        unsigned short* lds_b = (unsigned short*)(smem + 16384);  // 16384 B
        const int gblk = blk - NBUCK;          // 0..2345
        // XCD-chunked bijective swizzle: the 6 sharers of an m-tile on one XCD
        constexpr int SWQ = NB_GEMM / 8;   // 293
        constexpr int SWR = NB_GEMM % 8;   // 2
        const int xcd = gblk & 7, pos = gblk >> 3;
        const int my = (xcd < SWR ? xcd * (SWQ + 1)
                                  : SWR * (SWQ + 1) + (xcd - SWR) * SWQ) + pos;
        const int mt  = my / 6;
        const int rem = my % 6;                // sharers of m-tile adjacent
        const int m0 = mt * 128;
        const int n0 = (rem & 1) * 128;
        const int s  = rem >> 1;
        const unsigned short* wt = Wt + (size_t)s * D_OUT * D_IN;
        const int wave = tid >> 6;
        const int lane = tid & 63;
        const int quad = lane >> 4;
        const int lo   = lane & 15;
        const int wm = (wave & 1) * 64;
        const int wn = (wave >> 1) * 64;

        f32x4 acc[4][4] = {};

        for (int kb = 0; kb < D_IN; kb += 64) {
            __syncthreads();
            #pragma unroll
            for (int c = 0; c < 4; ++c) {
                int idx = c * 256 + tid;
                int row = idx >> 3;
                int kp  = idx & 7;
                const unsigned short* ga = xb + (size_t)(m0 + row) * D_IN + kb + kp * 8;
                __builtin_amdgcn_global_load_lds((glb_u32_t*)ga,
                                                 (lds_u32_t*)&lds_a[idx * 8], 16, 0, 0);
                const unsigned short* gb = wt + (size_t)(n0 + row) * D_IN + kb + kp * 8;
                __builtin_amdgcn_global_load_lds((glb_u32_t*)gb,
                                                 (lds_u32_t*)&lds_b[idx * 8], 16, 0, 0);
            }
            __syncthreads();

            #pragma unroll
            for (int t = 0; t < 2; ++t) {
                bf16x8 af[4], bfr[4];
                #pragma unroll
                for (int i = 0; i < 4; ++i)
                    af[i] = *(const bf16x8*)&lds_a[(wm + 16 * i + lo) * 64 + t * 32 + quad * 8];
                #pragma unroll
                for (int j = 0; j < 4; ++j)
                    bfr[j] = *(const bf16x8*)&lds_b[(wn + 16 * j + lo) * 64 + t * 32 + quad * 8];
                #pragma unroll
                for (int i = 0; i < 4; ++i)
                    #pragma unroll
                    for (int j = 0; j < 4; ++j)
                        acc[i][j] = __builtin_amdgcn_mfma_f32_16x16x32_bf16(af[i], bfr[j], acc[i][j], 0, 0, 0);
            }
        }

        // epilogue: C layout col=lane&15, row=quad*4+reg
        #pragma unroll
        for (int i = 0; i < 4; ++i) {
            #pragma unroll
            for (int j = 0; j < 4; ++j) {
                int gn = n0 + wn + 16 * j + lo;
                #pragma unroll
                for (int r = 0; r < 4; ++r) {
                    int gm2 = m0 + wm + 16 * i + quad * 4 + r;
                    if (gm2 < N_NODES)
                        pre[((size_t)s * N_NODES + gm2) * D_OUT + gn] = f2bf(acc[i][j][r]);
                }
            }
        }
    }
}

// ---------------- fused SpMM (combined CSR) + ReLU, unroll x16/8/4/1 --------------
__global__ __launch_bounds__(256) void spmm_kernel(const unsigned short* __restrict__ pre,
                                                   const int* __restrict__ base,
                                                   const int* __restrict__ cnt,
                                                   const int2* __restrict__ cv,
                                                   float* __restrict__ out) {
    int row  = blockIdx.x * 4 + (threadIdx.x >> 6);
    int lane = threadIdx.x & 63;
    int start = base[row];
    int end   = start + cnt[row];
    float a0 = 0.f, a1 = 0.f, a2 = 0.f, a3 = 0.f;
    int j = start;
    for (; j + 16 <= end; j += 16) {
        int2 e[16];
        #pragma unroll
        for (int q = 0; q < 16; ++q) e[q] = ldnt_int2(&cv[j + q]);
        ushort4 p[16];
        #pragma unroll
        for (int q = 0; q < 16; ++q)
            p[q] = *(const ushort4*)(pre + (size_t)e[q].x * D_OUT + lane * 4);
        #pragma unroll
        for (int q = 0; q < 16; ++q) {
            float w = __int_as_float(e[q].y);
            a0 += w * bf2f(p[q].x);
            a1 += w * bf2f(p[q].y);
            a2 += w * bf2f(p[q].z);
            a3 += w * bf2f(p[q].w);
        }
    }
    for (; j + 8 <= end; j += 8) {
        int2 e[8];
        #pragma unroll
        for (int q = 0; q < 8; ++q) e[q] = ldnt_int2(&cv[j + q]);
        ushort4 p[8];
        #pragma unroll
        for (int q = 0; q < 8; ++q)
            p[q] = *(const ushort4*)(pre + (size_t)e[q].x * D_OUT + lane * 4);
        #pragma unroll
        for (int q = 0; q < 8; ++q) {
            float w = __int_as_float(e[q].y);
            a0 += w * bf2f(p[q].x);
            a1 += w * bf2f(p[q].y);
            a2 += w * bf2f(p[q].z);
            a3 += w * bf2f(p[q].w);
        }
    }
    for (; j + 4 <= end; j += 4) {
        int2 e[4];
        #pragma unroll
        for (int q = 0; q < 4; ++q) e[q] = ldnt_int2(&cv[j + q]);
        ushort4 p[4];
        #pragma unroll
        for (int q = 0; q < 4; ++q)
            p[q] = *(const ushort4*)(pre + (size_t)e[q].x * D_OUT + lane * 4);
        #pragma unroll
        for (int q = 0; q < 4; ++q) {
            float w = __int_as_float(e[q].y);
            a0 += w * bf2f(p[q].x);
            a1 += w * bf2f(p[q].y);
            a2 += w * bf2f(p[q].z);
            a3 += w * bf2f(p[q].w);
        }
    }
    for (; j < end; ++j) {
        int2 e = ldnt_int2(&cv[j]);
        float w = __int_as_float(e.y);
        ushort4 p = *(const ushort4*)(pre + (size_t)e.x * D_OUT + lane * 4);
        a0 += w * bf2f(p.x);
        a1 += w * bf2f(p.y);
        a2 += w * bf2f(p.z);
        a3 += w * bf2f(p.w);
    }
    f32x4 o;
    o.x = fmaxf(a0, 0.f);
    o.y = fmaxf(a1, 0.f);
    o.z = fmaxf(a2, 0.f);
    o.w = fmaxf(a3, 0.f);
    __builtin_nontemporal_store(o, (f32x4*)(out + (size_t)row * D_OUT + lane * 4));
}

extern "C" void kernel_launch(void* const* d_in, const int* in_sizes, int n_in,
                              void* d_out, int out_size, void* d_ws, size_t ws_size,
                              hipStream_t stream) {
    const float* x    = (const float*)d_in[0];
    const float* W    = (const float*)d_in[1];
    const int*   rows = (const int*)d_in[2];
    const int*   cols = (const int*)d_in[3];
    const float* vals = (const float*)d_in[4];
    const float* cw   = (const float*)d_in[5];
    float* out = (float*)d_out;

    char* ws = (char*)d_ws;
    size_t off = 0;
    auto alloc = [&](size_t bytes) -> void* {
        void* p = ws + off;
        off += (bytes + 255) & ~(size_t)255;
        return p;
    };
    unsigned short* pre  = (unsigned short*)alloc((size_t)SUP * N_NODES * D_OUT * 2); // 76.8 MB
    unsigned short* xb   = (unsigned short*)alloc((size_t)N_PAD * D_IN * 2);          // 51.25 MB
    unsigned short* Wt   = (unsigned short*)alloc((size_t)SUP * D_OUT * D_IN * 2);    // 0.8 MB
    int* base            = (int*)alloc((size_t)N_NODES * 4);
    int* cnt             = (int*)alloc((size_t)N_NODES * 4);
    int* bucket_cursor   = (int*)alloc((size_t)NBUCK * 4);
    int2* cv             = (int2*)alloc((size_t)NBUCK * CAP * 8);                     // 23.0 MB
    // buck lives in d_out (51.2 MB >= 23.0 MB): written by prepbucket, read by
    // sortgemm, dead before spmm overwrites out.
    int2* buck           = (int2*)d_out;

    hipMemsetAsync(bucket_cursor, 0, (size_t)NBUCK * 4, stream);

    prepbucket_kernel<<<NBB + NB_XPREP + NB_WPREP, 256, 0, stream>>>(
        rows, cols, vals, cw, bucket_cursor, buck, x, (unsigned int*)xb, W, Wt);
    sortgemm_kernel<<<NBUCK + NB_GEMM, 256, 0, stream>>>(
        buck, bucket_cursor, cv, base, cnt, xb, Wt, pre);
    spmm_kernel<<<N_NODES / 4, 256, 0, stream>>>(pre, base, cnt, cv, out);
}